// Round 5
// baseline (258.044 us; speedup 1.0000x reference)
//
#include <hip/hip_runtime.h>
#include <hip/hip_bf16.h>
#include <limits.h>

#define NSEG 200
#define STRENGTH 1e-3f
#define NB 4096                 // coarse buckets per segment
#define LOG_NB 12
#define M_TOT (NSEG * NB)
#define HCHUNK 8192             // elements per hist/scatter block
#define ECHUNK 2048             // elements per emd block
#define WCAP 2560               // LDS window capacity (ECHUNK + 2*max_bucket)
#define BCAP 2052               // staged bucket-ends capacity (span+2)

__device__ __forceinline__ int bucket_of(float x, float scale) {
    float t = (x + 6.0f) * scale;   // scale = NB/12
    int b = (int)floorf(t);
    b = b < 0 ? 0 : (b > NB - 1 ? NB - 1 : b);
    return b;
}

// ---- 0. segment boundaries from sorted seg ids + zero counts/segSums ----
__global__ void k_bounds(const int* __restrict__ seg, int* __restrict__ seg_starts,
                         int* __restrict__ counts, float* __restrict__ segSums, int N) {
    int stride = gridDim.x * blockDim.x;
    int tid = blockIdx.x * blockDim.x + threadIdx.x;
    for (int k = tid; k < M_TOT; k += stride) counts[k] = 0;
    for (int k = tid; k < NSEG; k += stride) segSums[k] = 0.f;
    if (tid == 0) { seg_starts[0] = 0; seg_starts[NSEG] = N; }
    const int4* s4 = (const int4*)seg;
    int N4 = N >> 2;
    for (int i = tid; i < N4; i += stride) {
        int4 s = s4[i];
        int prev = (i == 0) ? s.x : seg[i * 4 - 1];
        if (s.x != prev) seg_starts[s.x] = i * 4;
        if (s.y != s.x) seg_starts[s.y] = i * 4 + 1;
        if (s.z != s.y) seg_starts[s.z] = i * 4 + 2;
        if (s.w != s.z) seg_starts[s.w] = i * 4 + 3;
    }
}

// ---- 1. histogram of (segment, bucket) via per-block LDS hist ----
__global__ void __launch_bounds__(512)
k_hist(const float* __restrict__ x, const int* __restrict__ seg_starts,
       int* __restrict__ counts, int N, float scale) {
    __shared__ int h[2 * NB];
    __shared__ int sst[NSEG + 1];
    int t = threadIdx.x;
    for (int k = t; k < NSEG + 1; k += 512) sst[k] = seg_starts[k];
    for (int k = t; k < 2 * NB; k += 512) h[k] = 0;
    __syncthreads();
    int base = blockIdx.x * HCHUNK;
    int lo = 0, hi = NSEG - 1;
    while (lo < hi) { int mid = (lo + hi) >> 1; if (base < sst[mid + 1]) hi = mid; else lo = mid + 1; }
    int s0 = lo, bnd = sst[lo + 1];
    const float4* x4 = (const float4*)x;
    for (int it = 0; it < HCHUNK / (512 * 4); ++it) {
        int j = (it * 512 + t) * 4;
        int gi = base + j;
        if (gi < N) {
            float4 v = x4[(base >> 2) + it * 512 + t];
            int sel0 = (gi + 0) >= bnd ? NB : 0;
            int sel1 = (gi + 1) >= bnd ? NB : 0;
            int sel2 = (gi + 2) >= bnd ? NB : 0;
            int sel3 = (gi + 3) >= bnd ? NB : 0;
            atomicAdd(&h[sel0 + bucket_of(v.x, scale)], 1);
            atomicAdd(&h[sel1 + bucket_of(v.y, scale)], 1);
            atomicAdd(&h[sel2 + bucket_of(v.z, scale)], 1);
            atomicAdd(&h[sel3 + bucket_of(v.w, scale)], 1);
        }
    }
    __syncthreads();
    for (int k = t; k < 2 * NB; k += 512) {
        int c = h[k];
        if (c > 0) atomicAdd(&counts[(s0 + (k >= NB)) * NB + (k & (NB - 1))], c);
    }
}

// ---- 2. exclusive scan over M_TOT counters ----
__global__ void k_scan_partial(const int* __restrict__ counts, int* __restrict__ partials, int M) {
    __shared__ int sdata[256];
    int base = blockIdx.x * 2048;
    int sum = 0;
    for (int k = threadIdx.x; k < 2048; k += 256) {
        int idx = base + k;
        sum += (idx < M) ? counts[idx] : 0;
    }
    sdata[threadIdx.x] = sum;
    __syncthreads();
    for (int off = 128; off > 0; off >>= 1) {
        if (threadIdx.x < off) sdata[threadIdx.x] += sdata[threadIdx.x + off];
        __syncthreads();
    }
    if (threadIdx.x == 0) partials[blockIdx.x] = sdata[0];
}

__global__ void k_scan_carry(int* __restrict__ partials, int nb) {
    __shared__ int bufA[1024], bufB[1024];
    int t = threadIdx.x;
    int v = (t < nb) ? partials[t] : 0;
    int* src = bufA; int* dst = bufB;
    src[t] = v;
    __syncthreads();
    for (int off = 1; off < 1024; off <<= 1) {
        dst[t] = src[t] + ((t >= off) ? src[t - off] : 0);
        __syncthreads();
        int* tmp = src; src = dst; dst = tmp;
    }
    if (t < nb) partials[t] = src[t] - v;   // exclusive
}

__global__ void k_scan_final(const int* __restrict__ counts, const int* __restrict__ partials,
                             int* __restrict__ cursor, int* __restrict__ seg_ends, int M) {
    __shared__ int tile[2048];
    __shared__ int sa[256], sb[256];
    int t = threadIdx.x;
    int base = blockIdx.x * 2048;
    for (int k = t; k < 2048; k += 256) {
        int idx = base + k;
        tile[k] = (idx < M) ? counts[idx] : 0;
    }
    __syncthreads();
    int loc[8]; int run = 0;
    for (int k = 0; k < 8; ++k) { loc[k] = run; run += tile[t * 8 + k]; }
    int v = run;
    int* src = sa; int* dst = sb;
    __syncthreads();
    src[t] = v;
    __syncthreads();
    for (int off = 1; off < 256; off <<= 1) {
        int w = src[t] + ((t >= off) ? src[t - off] : 0);
        dst[t] = w;
        __syncthreads();
        int* tmp = src; src = dst; dst = tmp;
    }
    int texcl = src[t] - v;
    int gbase = partials[blockIdx.x];
    for (int k = 0; k < 8; ++k) {
        int idx = base + t * 8 + k;
        if (idx < M) {
            int excl = gbase + texcl + loc[k];
            cursor[idx] = excl;
            if (((idx + 1) & (NB - 1)) == 0)
                seg_ends[(idx + 1 >> LOG_NB) - 1] = excl + tile[t * 8 + k];  // inclusive at seg end
        }
    }
}

// ---- 3. scatter with per-block reservation (cursor: starts -> ends) ----
__global__ void __launch_bounds__(512)
k_scatter(const float* __restrict__ x, const int* __restrict__ seg_starts,
          int* __restrict__ cursor, float* __restrict__ sx, int N, float scale) {
    __shared__ int h[2 * NB];
    __shared__ unsigned short lr[HCHUNK];
    __shared__ int sst[NSEG + 1];
    int t = threadIdx.x;
    for (int k = t; k < NSEG + 1; k += 512) sst[k] = seg_starts[k];
    for (int k = t; k < 2 * NB; k += 512) h[k] = 0;
    __syncthreads();
    int base = blockIdx.x * HCHUNK;
    int lo = 0, hi = NSEG - 1;
    while (lo < hi) { int mid = (lo + hi) >> 1; if (base < sst[mid + 1]) hi = mid; else lo = mid + 1; }
    int s0 = lo, bnd = sst[lo + 1];
    const float4* x4 = (const float4*)x;
    // pass 1: local ranks
    for (int it = 0; it < HCHUNK / (512 * 4); ++it) {
        int j = (it * 512 + t) * 4;
        int gi = base + j;
        if (gi < N) {
            float4 v = x4[(base >> 2) + it * 512 + t];
            int g0 = ((gi + 0) >= bnd ? NB : 0) + bucket_of(v.x, scale);
            int g1 = ((gi + 1) >= bnd ? NB : 0) + bucket_of(v.y, scale);
            int g2 = ((gi + 2) >= bnd ? NB : 0) + bucket_of(v.z, scale);
            int g3 = ((gi + 3) >= bnd ? NB : 0) + bucket_of(v.w, scale);
            lr[j + 0] = (unsigned short)atomicAdd(&h[g0], 1);
            lr[j + 1] = (unsigned short)atomicAdd(&h[g1], 1);
            lr[j + 2] = (unsigned short)atomicAdd(&h[g2], 1);
            lr[j + 3] = (unsigned short)atomicAdd(&h[g3], 1);
        }
    }
    __syncthreads();
    // reserve: h[k] becomes global base for this block's (seg,bucket) group
    for (int k = t; k < 2 * NB; k += 512) {
        int c = h[k];
        if (c > 0) h[k] = atomicAdd(&cursor[(s0 + (k >= NB)) * NB + (k & (NB - 1))], c);
    }
    __syncthreads();
    // pass 2: write
    for (int it = 0; it < HCHUNK / (512 * 4); ++it) {
        int j = (it * 512 + t) * 4;
        int gi = base + j;
        if (gi < N) {
            float4 v = x4[(base >> 2) + it * 512 + t];
            int g0 = ((gi + 0) >= bnd ? NB : 0) + bucket_of(v.x, scale);
            int g1 = ((gi + 1) >= bnd ? NB : 0) + bucket_of(v.y, scale);
            int g2 = ((gi + 2) >= bnd ? NB : 0) + bucket_of(v.z, scale);
            int g3 = ((gi + 3) >= bnd ? NB : 0) + bucket_of(v.w, scale);
            sx[h[g0] + lr[j + 0]] = v.x;
            sx[h[g1] + lr[j + 1]] = v.y;
            sx[h[g2] + lr[j + 2]] = v.z;
            sx[h[g3] + lr[j + 3]] = v.w;
        }
    }
}

// ---- 4. rank within bucket via LDS windows (sx, y, bucket-ends all staged) ----
__global__ void __launch_bounds__(256)
k_emd(const float* __restrict__ sx, const float* __restrict__ y,
      const int* __restrict__ ends, const int* __restrict__ seg_ends,
      float* __restrict__ segSums, int N, float scale) {
    __shared__ float win[WCAP];
    __shared__ float ywin[WCAP];
    __shared__ int bends[BCAP];
    __shared__ int sEnd[NSEG];
    __shared__ int sh[5];
    int tid = threadIdx.x;
    for (int k = tid; k < NSEG; k += 256) sEnd[k] = seg_ends[k];
    __syncthreads();
    int pbase = blockIdx.x * ECHUNK;
    int pend = min(pbase + ECHUNK, N);
    if (tid == 0) {
        float v = sx[pbase];
        int lo = 0, hi = NSEG - 1;
        while (lo < hi) { int mid = (lo + hi) >> 1; if (pbase < sEnd[mid]) hi = mid; else lo = mid + 1; }
        int g = lo * NB + bucket_of(v, scale);
        sh[0] = (g == 0) ? 0 : ends[g - 1];
        sh[2] = lo;
        sh[3] = g;
    }
    if (tid == 255) {
        float v = sx[pend - 1];
        int lo = 0, hi = NSEG - 1;
        while (lo < hi) { int mid = (lo + hi) >> 1; if (pend - 1 < sEnd[mid]) hi = mid; else lo = mid + 1; }
        int g = lo * NB + bucket_of(v, scale);
        sh[1] = ends[g];
        sh[4] = g;
    }
    __syncthreads();
    int wlo = sh[0], whi = sh[1], s0 = sh[2], gfirst = sh[3], glast = sh[4];
    int wsz = whi - wlo;
    bool fits = wsz <= WCAP;
    int bcount = glast - gfirst + 2;
    bool useB = fits && bcount <= BCAP;
    if (fits) {
        for (int k = tid; k < wsz; k += 256) { win[k] = sx[wlo + k]; ywin[k] = y[wlo + k]; }
    }
    if (useB) {
        for (int k = tid; k < bcount; k += 256) {
            int g = gfirst - 1 + k;
            bends[k] = (g < 0) ? 0 : ends[g];
        }
    }
    __syncthreads();

    float acc0 = 0.f, acc1 = 0.f;
    if (fits) {
        for (int e = 0; e < ECHUNK / 256; ++e) {
            int p = pbase + (e << 8) + tid;
            if (p >= pend) break;
            int s = s0;
            while (p >= sEnd[s]) ++s;
            int widx = p - wlo;
            float v = win[widx];
            int g = s * NB + bucket_of(v, scale);
            int start, end;
            if (useB) { start = bends[g - gfirst]; end = bends[g - gfirst + 1]; }
            else { start = (g == 0) ? 0 : ends[g - 1]; end = ends[g]; }
            int a = start - wlo, bq = end - wlo;
            int rank = 0;
            int k = a;
            for (; k < bq && (k & 3); ++k) { float vj = win[k]; rank += (vj < v) || (vj == v && k < widx); }
            for (; k + 3 < bq; k += 4) {
                float4 q = *(const float4*)&win[k];
                rank += (q.x < v) || (q.x == v && (k)     < widx);
                rank += (q.y < v) || (q.y == v && (k + 1) < widx);
                rank += (q.z < v) || (q.z == v && (k + 2) < widx);
                rank += (q.w < v) || (q.w == v && (k + 3) < widx);
            }
            for (; k < bq; ++k) { float vj = win[k]; rank += (vj < v) || (vj == v && k < widx); }
            float diff = fabsf(v - ywin[a + rank]);
            if (s == s0) acc0 += diff;
            else if (s == s0 + 1) acc1 += diff;
            else atomicAdd(&segSums[s], diff);
        }
    } else {
        // global fallback (window exceeds LDS — should not happen at these sizes)
        for (int e = 0; e < ECHUNK / 256; ++e) {
            int p = pbase + (e << 8) + tid;
            if (p >= pend) break;
            int s = s0;
            while (p >= sEnd[s]) ++s;
            float v = sx[p];
            int g = s * NB + bucket_of(v, scale);
            int start = (g == 0) ? 0 : ends[g - 1];
            int end = ends[g];
            int rank = 0;
            for (int j = start; j < end; ++j) { float vj = sx[j]; rank += (vj < v) || (vj == v && j < p); }
            float diff = fabsf(v - y[start + rank]);
            if (s == s0) acc0 += diff;
            else if (s == s0 + 1) acc1 += diff;
            else atomicAdd(&segSums[s], diff);
        }
    }

    for (int off = 32; off > 0; off >>= 1) {
        acc0 += __shfl_xor(acc0, off);
        acc1 += __shfl_xor(acc1, off);
    }
    if ((tid & 63) == 0) {
        if (acc0 != 0.f) atomicAdd(&segSums[s0], acc0);
        if (acc1 != 0.f && s0 + 1 < NSEG) atomicAdd(&segSums[s0 + 1], acc1);
    }
}

// ---- 5. finalize ----
__global__ void k_final(const float* __restrict__ segSums, const int* __restrict__ seg_ends,
                        float* __restrict__ out) {
    __shared__ float red[256];
    int t = threadIdx.x;
    float acc = 0.f;
    for (int s = t; s < NSEG; s += 256) {
        int end = seg_ends[s];
        int st = (s == 0) ? 0 : seg_ends[s - 1];
        float cnt = (float)(end - st);
        acc += segSums[s] / fmaxf(cnt, 1.0f);
    }
    red[t] = acc;
    __syncthreads();
    for (int off = 128; off > 0; off >>= 1) {
        if (t < off) red[t] += red[t + off];
        __syncthreads();
    }
    if (t == 0) out[0] = red[0] * (1.0f / (float)NSEG) * STRENGTH;
}

extern "C" void kernel_launch(void* const* d_in, const int* in_sizes, int n_in,
                              void* d_out, int out_size, void* d_ws, size_t ws_size,
                              hipStream_t stream) {
    const float* x = (const float*)d_in[0];
    const float* y = (const float*)d_in[1];          // initial_sorted
    const int* seg = (const int*)d_in[2];            // segment_ids (sorted)
    int N = in_sizes[0];
    float scale = (float)NB / 12.0f;

    char* ws = (char*)d_ws;
    float* sx        = (float*)ws;                        // N floats
    int*   counts    = (int*)(ws + (size_t)N * 4);        // M_TOT ints
    int*   cursor    = counts + M_TOT;                    // M_TOT ints
    int*   partials  = cursor + M_TOT;                    // <=1024 ints
    float* segSums   = (float*)(partials + 1024);         // NSEG floats
    int*   seg_ends  = (int*)(segSums + NSEG);            // NSEG ints
    int*   seg_starts= seg_ends + NSEG;                   // NSEG+1 ints

    int nb = (M_TOT + 2047) / 2048;    // = 400
    int nchunk = (N + HCHUNK - 1) / HCHUNK;

    k_bounds<<<256, 256, 0, stream>>>(seg, seg_starts, counts, segSums, N);
    k_hist<<<nchunk, 512, 0, stream>>>(x, seg_starts, counts, N, scale);
    k_scan_partial<<<nb, 256, 0, stream>>>(counts, partials, M_TOT);
    k_scan_carry<<<1, 1024, 0, stream>>>(partials, nb);
    k_scan_final<<<nb, 256, 0, stream>>>(counts, partials, cursor, seg_ends, M_TOT);
    k_scatter<<<nchunk, 512, 0, stream>>>(x, seg_starts, cursor, sx, N, scale);
    k_emd<<<(N + ECHUNK - 1) / ECHUNK, 256, 0, stream>>>(sx, y, cursor, seg_ends, segSums, N, scale);
    k_final<<<1, 256, 0, stream>>>(segSums, seg_ends, (float*)d_out);
}